// Round 21
// baseline (736.899 us; speedup 1.0000x reference)
//
#include <hip/hip_runtime.h>
#include <stdint.h>
#include <math.h>

// RNN predictor: B=2048, T=1024 teacher + FUT=64 AR, H=128.
// Round-21: R20's 4-independent-2-wave-blocks/CU geometry with the sample
// placement FIXED to the verified convention (R20 bug: samples sit at A-rows
// {0,4}, so sample s -> C-(row 4s, reg 0) = lane-group g=s, reg 0; R20 read
// C regs [0],[1] at g==0 and computed garbage for sample 1).
//  - SPB=2, NT=128 (2 waves), grid=1024, __launch_bounds__(128,2):
//    4 blocks/CU, 2 waves/SIMD from different blocks (anti-phased chains).
//  - wave w owns 4 j-tiles (cols 64w+16q+l15): 16 S-MFMA + 4 o-MFMA.
//  - pi-layout byte(k) = (k&15)*16 + 2*(k>>4): h'[j_q] bytes are contiguous
//    over q -> each g<2 lane writes 8B (2 u32) at row g, XOR (g<<5).
//  - o at lanes 0 (sample 0) and 16 (sample 1); AR feedback via one shfl.
//  - single-fp16 weights; split teacher/AR loops; one barrier/step;
//    64-entry o ring flushed as f32x4. All R17-verified pieces.

#define TLEN  1024
#define FUT   64
#define HID   128
#define SPB   2
#define NT    128
#define NSTEP (TLEN + FUT)

typedef float f32x4 __attribute__((ext_vector_type(4)));
typedef _Float16 f16x8 __attribute__((ext_vector_type(8)));
typedef uint32_t u32x4 __attribute__((ext_vector_type(4)));

__device__ __forceinline__ f16x8 asf16(u32x4 v) {
    return __builtin_bit_cast(f16x8, v);
}
__device__ __forceinline__ float fast_tanh(float v) {
    return 1.0f - 2.0f / (__expf(2.0f * v) + 1.0f);   // saturates correctly
}
__device__ __forceinline__ uint32_t packh(float a, float b) {
    return (uint32_t)__builtin_bit_cast(unsigned short, (_Float16)a)
         | ((uint32_t)__builtin_bit_cast(unsigned short, (_Float16)b) << 16);
}

__global__ __launch_bounds__(NT, 2) void rnn_kernel(
    const float* __restrict__ x,      // [B, T]
    const float* __restrict__ W_ih,   // [H, 1]
    const float* __restrict__ W_hh,   // [H, H]
    const float* __restrict__ b_ih,   // [H]
    const float* __restrict__ b_hh,   // [H]
    const float* __restrict__ W_out,  // [1, H]
    const float* __restrict__ b_out,  // [1]
    float* __restrict__ out)          // [B, T+FUT]
{
    // h: [p][row s=0..1][pi(k)] fp16, row 256B, byte ^= (s<<5) both sides
    __shared__ __align__(16) unsigned short hbuf[2][SPB * HID];  // 1KB
    __shared__ __align__(16) float xstg[128][SPB];               // 1KB
    __shared__ __align__(16) float ring[2][SPB][68];             // o ring

    const int tid  = threadIdx.x;
    const int lane = tid & 63;
    const int wid  = tid >> 6;        // wave w in {0,1}: cols 64w..64w+63
    const int l15  = lane & 15;
    const int g    = lane >> 4;       // sample index for g < SPB
    const int s0   = blockIdx.x * SPB;

    // ---- weight B-fragments, single fp16; slot(kt,g,e) -> k=16e+4kt+g ----
    f16x8 W_[4][4], Wo[4];            // W_[q][kt], cols j_q = 64w+16q+l15
    float bias[4], wih[4];
    #pragma unroll
    for (int q = 0; q < 4; ++q) {
        const int j = 64 * wid + 16 * q + l15;
        const float* r0 = W_hh + (size_t)j * HID;
        #pragma unroll
        for (int kt = 0; kt < 4; ++kt) {
            #pragma unroll
            for (int e = 0; e < 8; ++e) {
                const int k = 16 * e + 4 * kt + g;
                W_[q][kt][e] = (_Float16)r0[k];
            }
        }
        bias[q] = b_ih[j] + b_hh[j];
        wih[q]  = W_ih[j];
    }
    #pragma unroll
    for (int kt = 0; kt < 4; ++kt)
        #pragma unroll
        for (int e = 0; e < 8; ++e) {
            const int k = 16 * e + 4 * kt + g;
            Wo[kt][e] = (l15 == 0) ? (_Float16)W_out[k] : (_Float16)0.0f;
        }
    const float bo = b_out[0];

    // ---- LDS byte offsets ----
    // A-read: lanes l15 in {0,4} read hbuf row s_=l15>>2 (-> A rows 0,4).
    const int s_ = l15 >> 2;
    int aoff[4];
    #pragma unroll
    for (int kt = 0; kt < 4; ++kt)
        aoff[kt] = s_ * 256 + (((4 * kt + g) * 16) ^ (s_ << 5));
    // h'-write (lanes g<SPB): row g, 8B at (l15*16 + 8*wid) ^ (g<<5)
    const int woff = g * 256 + ((l15 * 16 + 8 * wid) ^ (g << 5));

    for (int idx = tid; idx < SPB * HID; idx += NT)   // 256 u32 = both parities
        ((uint32_t*)hbuf)[idx] = 0;
    __syncthreads();

    // A-frags zeroed once; masked loads keep inactive lanes at zero.
    u32x4 A_[4];
    #pragma unroll
    for (int kt = 0; kt < 4; ++kt) A_[kt] = (u32x4){0, 0, 0, 0};

    // ================= teacher-forced loop =================
    #pragma unroll 2
    for (int i = 0; i < TLEN; ++i) {
        const int p = i & 1;

        if ((i & 127) == 0) {         // refill x chunk (2 passes of 128)
            #pragma unroll
            for (int pass = 0; pass < 2; ++pass) {
                const int idx = pass * NT + tid;
                const int t = idx & 127, s = idx >> 7;
                xstg[t][s] = x[(size_t)(s0 + s) * TLEN + (i + t)];
            }
            __syncthreads();
        }
        if (i > 64 && (i & 63) == 1 && tid < 16 * SPB) {   // flush o ring
            const int q = ((i - 65) >> 6) & 1;
            const int s = tid >> 4, c4 = (tid & 15) * 4;
            const f32x4 v = *(const f32x4*)&ring[q][s][c4];
            *(f32x4*)&out[(size_t)(s0 + s) * NSTEP + (i - 65) + c4] = v;
        }

        const char* hb = (const char*)hbuf[p];
        if (l15 < 8 && (l15 & 3) == 0) {
            #pragma unroll
            for (int kt = 0; kt < 4; ++kt)
                A_[kt] = *(const u32x4*)(hb + aoff[kt]);
        }

        // 20 MFMA: 4 S-tile chains + 1 o chain
        f32x4 s0v = {0.f,0.f,0.f,0.f}, s1v = s0v, s2v = s0v, s3v = s0v, ov = s0v;
        #pragma unroll
        for (int kt = 0; kt < 4; ++kt) {
            s0v = __builtin_amdgcn_mfma_f32_16x16x32_f16(asf16(A_[kt]), W_[0][kt], s0v, 0, 0, 0);
            s1v = __builtin_amdgcn_mfma_f32_16x16x32_f16(asf16(A_[kt]), W_[1][kt], s1v, 0, 0, 0);
            s2v = __builtin_amdgcn_mfma_f32_16x16x32_f16(asf16(A_[kt]), W_[2][kt], s2v, 0, 0, 0);
            s3v = __builtin_amdgcn_mfma_f32_16x16x32_f16(asf16(A_[kt]), W_[3][kt], s3v, 0, 0, 0);
            ov  = __builtin_amdgcn_mfma_f32_16x16x32_f16(asf16(A_[kt]), Wo[kt],    ov,  0, 0, 0);
        }

        // o_{i-1}[sample g] at lanes (g<SPB, l15==0): C row 4g, reg 0
        if (i > 0 && wid == 0 && l15 == 0 && g < SPB)
            ring[((i - 1) >> 6) & 1][g][(i - 1) & 63] = ov[0] + bo;

        // epilogue at lanes g<SPB: sample g x cols q=0..3 (C reg 0)
        if (g < SPB) {
            const float in = xstg[i & 127][g];
            const float h0 = fast_tanh(s0v[0] + bias[0] + in * wih[0]);
            const float h1 = fast_tanh(s1v[0] + bias[1] + in * wih[1]);
            const float h2 = fast_tanh(s2v[0] + bias[2] + in * wih[2]);
            const float h3 = fast_tanh(s3v[0] + bias[3] + in * wih[3]);
            char* hw = (char*)hbuf[p ^ 1] + woff;
            *(uint32_t*)(hw)     = packh(h0, h1);
            *(uint32_t*)(hw + 4) = packh(h2, h3);
        }
        __syncthreads();
    }

    // ================= autoregressive loop =================
    #pragma unroll 2
    for (int i = TLEN; i < NSTEP; ++i) {
        const int p = i & 1;

        if ((i & 63) == 1 && tid < 16 * SPB) {   // flush (fires at i=1025)
            const int q = ((i - 65) >> 6) & 1;
            const int s = tid >> 4, c4 = (tid & 15) * 4;
            const f32x4 v = *(const f32x4*)&ring[q][s][c4];
            *(f32x4*)&out[(size_t)(s0 + s) * NSTEP + (i - 65) + c4] = v;
        }

        const char* hb = (const char*)hbuf[p];
        if (l15 < 8 && (l15 & 3) == 0) {
            #pragma unroll
            for (int kt = 0; kt < 4; ++kt)
                A_[kt] = *(const u32x4*)(hb + aoff[kt]);
        }

        f32x4 s0v = {0.f,0.f,0.f,0.f}, s1v = s0v, s2v = s0v, s3v = s0v, ov = s0v;
        #pragma unroll
        for (int kt = 0; kt < 4; ++kt) {
            s0v = __builtin_amdgcn_mfma_f32_16x16x32_f16(asf16(A_[kt]), W_[0][kt], s0v, 0, 0, 0);
            s1v = __builtin_amdgcn_mfma_f32_16x16x32_f16(asf16(A_[kt]), W_[1][kt], s1v, 0, 0, 0);
            s2v = __builtin_amdgcn_mfma_f32_16x16x32_f16(asf16(A_[kt]), W_[2][kt], s2v, 0, 0, 0);
            s3v = __builtin_amdgcn_mfma_f32_16x16x32_f16(asf16(A_[kt]), W_[3][kt], s3v, 0, 0, 0);
            ov  = __builtin_amdgcn_mfma_f32_16x16x32_f16(asf16(A_[kt]), Wo[kt],    ov,  0, 0, 0);
        }
        const float oval = ov[0] + bo;    // sample g at lanes (g<SPB, l15==0)
        if (wid == 0 && l15 == 0 && g < SPB)
            ring[((i - 1) >> 6) & 1][g][(i - 1) & 63] = oval;

        // feedback: sample (g&1)'s o sits at lane (g&1)*16
        const float in = __shfl(oval, (g & 1) << 4);
        if (g < SPB) {
            const float h0 = fast_tanh(s0v[0] + bias[0] + in * wih[0]);
            const float h1 = fast_tanh(s1v[0] + bias[1] + in * wih[1]);
            const float h2 = fast_tanh(s2v[0] + bias[2] + in * wih[2]);
            const float h3 = fast_tanh(s3v[0] + bias[3] + in * wih[3]);
            char* hw = (char*)hbuf[p ^ 1] + woff;
            *(uint32_t*)(hw)     = packh(h0, h1);
            *(uint32_t*)(hw + 4) = packh(h2, h3);
        }
        __syncthreads();
    }

    // tail: o_{NSTEP-1} = wout . h_{NSTEP} (state in hbuf[NSTEP&1] = [0])
    {
        const char* hb = (const char*)hbuf[NSTEP & 1];
        if (l15 < 8 && (l15 & 3) == 0) {
            #pragma unroll
            for (int kt = 0; kt < 4; ++kt)
                A_[kt] = *(const u32x4*)(hb + aoff[kt]);
        }
        f32x4 ov = {0.f,0.f,0.f,0.f};
        #pragma unroll
        for (int kt = 0; kt < 4; ++kt)
            ov = __builtin_amdgcn_mfma_f32_16x16x32_f16(asf16(A_[kt]), Wo[kt], ov, 0, 0, 0);
        if (wid == 0 && l15 == 0 && g < SPB)
            ring[0][g][63] = ov[0] + bo;        // (1087>>6)&1 = 0
    }
    __syncthreads();
    if (tid < 16 * SPB) {   // flush t = 1024..1087 (ring parity 0)
        const int s = tid >> 4, c4 = (tid & 15) * 4;
        const f32x4 v = *(const f32x4*)&ring[0][s][c4];
        *(f32x4*)&out[(size_t)(s0 + s) * NSTEP + TLEN + c4] = v;
    }
}

extern "C" void kernel_launch(void* const* d_in, const int* in_sizes, int n_in,
                              void* d_out, int out_size, void* d_ws, size_t ws_size,
                              hipStream_t stream) {
    const float* x     = (const float*)d_in[0];
    const float* W_ih  = (const float*)d_in[1];
    const float* W_hh  = (const float*)d_in[2];
    const float* b_ih  = (const float*)d_in[3];
    const float* b_hh  = (const float*)d_in[4];
    const float* W_out = (const float*)d_in[5];
    const float* b_out = (const float*)d_in[6];
    float* out = (float*)d_out;

    dim3 grid(2048 / SPB);   // 1024 blocks -> 4 per CU, all resident
    dim3 block(NT);
    rnn_kernel<<<grid, block, 0, stream>>>(x, W_ih, W_hh, b_ih, b_hh,
                                           W_out, b_out, out);
}